// Round 1
// baseline (3824.850 us; speedup 1.0000x reference)
//
#include <hip/hip_runtime.h>
#include <math.h>

namespace {

constexpr int nB = 16, nR = 400, nT = 400, nH = 8, nQ = 64;
constexpr int BH = nB * nH;   // 128
constexpr int HQ = nH * nQ;   // 512

// ---------------- generic fp32 GEMM: C = act(A@W + bias) [+ res] ----------------
// M % BM == 0, K % BK == 0 assumed. N guarded.
template<int BM, int BN, int BK, int TM, int TN, bool RELU, bool RES>
__global__ __launch_bounds__(256) void gemm_k(
    const float* __restrict__ A, const float* __restrict__ W,
    const float* __restrict__ bias, const float* res,
    float* C, int M, int N, int K)
{
  constexpr int NT = (BM / TM) * (BN / TN);
  static_assert(NT == 256, "block must be 256 threads");
  __shared__ float As[BK][BM + 4];
  __shared__ float Bs[BK][BN + 4];
  const int tid = threadIdx.x;
  const int bm = blockIdx.y * BM;
  const int bn = blockIdx.x * BN;
  const int tx = tid % (BN / TN);
  const int ty = tid / (BN / TN);
  const bool n4ok = ((N & 3) == 0);

  float acc[TM][TN];
#pragma unroll
  for (int i = 0; i < TM; ++i)
#pragma unroll
    for (int j = 0; j < TN; ++j) acc[i][j] = 0.f;

  for (int kt = 0; kt < K; kt += BK) {
#pragma unroll
    for (int i = 0; i < (BM * BK) / (NT * 4); ++i) {
      int flat = (tid + i * NT) * 4;
      int m = flat / BK;
      int k = flat % BK;
      float4 v = *(const float4*)(A + (size_t)(bm + m) * K + kt + k);
      As[k + 0][m] = v.x; As[k + 1][m] = v.y;
      As[k + 2][m] = v.z; As[k + 3][m] = v.w;
    }
#pragma unroll
    for (int i = 0; i < (BK * BN) / (NT * 4); ++i) {
      int flat = (tid + i * NT) * 4;
      int k = flat / BN;
      int n = flat % BN;
      int gn = bn + n;
      float4 v;
      if (n4ok && gn + 3 < N) {
        v = *(const float4*)(W + (size_t)(kt + k) * N + gn);
      } else {
        v.x = (gn + 0 < N) ? W[(size_t)(kt + k) * N + gn + 0] : 0.f;
        v.y = (gn + 1 < N) ? W[(size_t)(kt + k) * N + gn + 1] : 0.f;
        v.z = (gn + 2 < N) ? W[(size_t)(kt + k) * N + gn + 2] : 0.f;
        v.w = (gn + 3 < N) ? W[(size_t)(kt + k) * N + gn + 3] : 0.f;
      }
      *(float4*)&Bs[k][n] = v;
    }
    __syncthreads();
#pragma unroll
    for (int k = 0; k < BK; ++k) {
      float a[TM], b[TN];
#pragma unroll
      for (int i = 0; i < TM; i += 4)
        *(float4*)&a[i] = *(const float4*)&As[k][ty * TM + i];
#pragma unroll
      for (int j = 0; j < TN; j += 4)
        *(float4*)&b[j] = *(const float4*)&Bs[k][tx * TN + j];
#pragma unroll
      for (int i = 0; i < TM; ++i)
#pragma unroll
        for (int j = 0; j < TN; ++j) acc[i][j] += a[i] * b[j];
    }
    __syncthreads();
  }

#pragma unroll
  for (int i = 0; i < TM; ++i) {
    const int gm = bm + ty * TM + i;
    float* crow = C + (size_t)gm * N;
    const float* rrow = res + (size_t)gm * N;
#pragma unroll
    for (int j = 0; j < TN; j += 4) {
      const int gn = bn + tx * TN + j;
      if (n4ok && gn + 3 < N) {
        float4 bv = *(const float4*)(bias + gn);
        float4 v;
        v.x = acc[i][j + 0] + bv.x; v.y = acc[i][j + 1] + bv.y;
        v.z = acc[i][j + 2] + bv.z; v.w = acc[i][j + 3] + bv.w;
        if (RELU) {
          v.x = fmaxf(v.x, 0.f); v.y = fmaxf(v.y, 0.f);
          v.z = fmaxf(v.z, 0.f); v.w = fmaxf(v.w, 0.f);
        }
        if (RES) {
          float4 rv = *(const float4*)(rrow + gn);
          v.x += rv.x; v.y += rv.y; v.z += rv.z; v.w += rv.w;
        }
        *(float4*)(crow + gn) = v;
      } else {
#pragma unroll
        for (int jj = 0; jj < 4; ++jj) {
          int gnn = gn + jj;
          if (gnn < N) {
            float v = acc[i][j + jj] + bias[gnn];
            if (RELU) v = fmaxf(v, 0.f);
            if (RES) v += rrow[gnn];
            crow[gnn] = v;
          }
        }
      }
    }
  }
}

// ---------------- SE gate (gap == 1/R identically: softmax rows sum to 1) -------
__global__ void gate_k(const float* __restrict__ w1, const float* __restrict__ b1,
                       const float* __restrict__ w2, const float* __restrict__ b2,
                       float* gate)
{
  if (threadIdx.x == 0 && blockIdx.x == 0) {
    float h1[4];
    const float gap = 1.0f / 400.0f;
#pragma unroll
    for (int i = 0; i < 4; ++i) {
      float s = b1[i];
      for (int h = 0; h < 8; ++h) s += gap * w1[h * 4 + i];
      h1[i] = fmaxf(s, 0.f);
    }
#pragma unroll
    for (int h = 0; h < 8; ++h) {
      float s = b2[h];
      for (int i = 0; i < 4; ++i) s += h1[i] * w2[i * 8 + h];
      gate[h] = 1.f / (1.f + expf(-s));
    }
  }
}

// ---------------- fused scores -> relu -> softmax -> gate -> stable-rank mask ---
// One block handles 16 rows of one (b,h). Emits the 7-sparse adjacency rows.
__global__ __launch_bounds__(256) void attn_k(
    const float* __restrict__ qk, const float* __restrict__ gate,
    float* __restrict__ adjval, int* __restrict__ adjcol)
{
  __shared__ float Qs[16][68];
  __shared__ float Ks[64][68];
  __shared__ float sc[16][404];

  const int tid = threadIdx.x;
  const int blk = blockIdx.x;
  const int bh = blk / 25;
  const int rt = (blk % 25) * 16;
  const int b = bh / nH;
  const int h = bh % nH;
  const float* qkb = qk + (size_t)b * nR * HQ + h * nQ;

  {
    int r = tid >> 4;
    int q = (tid & 15) << 2;
    *(float4*)&Qs[r][q] = *(const float4*)(qkb + (size_t)(rt + r) * HQ + q);
  }

  const int r0 = (tid & 7) * 2;
  const int s0 = (tid >> 3) * 2;

  for (int st = 0; st < 7; ++st) {
    const int sn = st * 64;
    const int cnt = (nR - sn < 64) ? (nR - sn) : 64;
    __syncthreads();
#pragma unroll
    for (int i = 0; i < 4; ++i) {
      int flat = (tid + i * 256) * 4;
      int j = flat >> 6;
      int q = flat & 63;
      if (j < cnt)
        *(float4*)&Ks[j][q] = *(const float4*)(qkb + (size_t)(sn + j) * HQ + q);
    }
    __syncthreads();
    float a00 = 0.f, a01 = 0.f, a10 = 0.f, a11 = 0.f;
#pragma unroll
    for (int q4 = 0; q4 < 16; ++q4) {
      float4 qa = *(const float4*)&Qs[r0][q4 * 4];
      float4 qb = *(const float4*)&Qs[r0 + 1][q4 * 4];
      float4 ka = *(const float4*)&Ks[s0][q4 * 4];
      float4 kb = *(const float4*)&Ks[s0 + 1][q4 * 4];
      a00 += qa.x * ka.x + qa.y * ka.y + qa.z * ka.z + qa.w * ka.w;
      a01 += qa.x * kb.x + qa.y * kb.y + qa.z * kb.z + qa.w * kb.w;
      a10 += qb.x * ka.x + qb.y * ka.y + qb.z * ka.z + qb.w * ka.w;
      a11 += qb.x * kb.x + qb.y * kb.y + qb.z * kb.z + qb.w * kb.w;
    }
    if (s0 < cnt) {
      sc[r0][sn + s0]     = fmaxf(a00 * 0.125f, 0.f);
      sc[r0 + 1][sn + s0] = fmaxf(a10 * 0.125f, 0.f);
    }
    if (s0 + 1 < cnt) {
      sc[r0][sn + s0 + 1]     = fmaxf(a01 * 0.125f, 0.f);
      sc[r0 + 1][sn + s0 + 1] = fmaxf(a11 * 0.125f, 0.f);
    }
  }
  __syncthreads();

  // softmax over each row: 16 threads per row (lanes rt*16..rt*16+15, wave-aligned)
  const int tr = tid >> 4;
  const int tl = tid & 15;
  float m = 0.f;  // post-relu values >= 0, row max >= diag > 0
  for (int j = tl; j < nR; j += 16) m = fmaxf(m, sc[tr][j]);
#pragma unroll
  for (int o = 8; o > 0; o >>= 1) m = fmaxf(m, __shfl_xor(m, o));
  float ssum = 0.f;
  for (int j = tl; j < nR; j += 16) {
    float e = expf(sc[tr][j] - m);
    sc[tr][j] = e;
    ssum += e;
  }
#pragma unroll
  for (int o = 8; o > 0; o >>= 1) ssum += __shfl_xor(ssum, o);
  const float g = gate[h];
  for (int j = tl; j < nR; j += 16) sc[tr][j] = (sc[tr][j] / ssum) * g;
  __syncthreads();

  // stable-argsort ranks of special columns {0,16,17,18,19,20}:
  // rank(c) = #{v_j < v_c} + #{j < c : v_j == v_c}
  const int csp[6] = {0, 16, 17, 18, 19, 20};
  float vc[6];
#pragma unroll
  for (int i = 0; i < 6; ++i) vc[i] = sc[tr][csp[i]];
  int rk[6] = {0, 0, 0, 0, 0, 0};
  for (int j = tl; j < nR; j += 16) {
    float vj = sc[tr][j];
#pragma unroll
    for (int i = 0; i < 6; ++i)
      rk[i] += (vj < vc[i]) ? 1 : ((vj == vc[i] && j < csp[i]) ? 1 : 0);
  }
#pragma unroll
  for (int i = 0; i < 6; ++i)
#pragma unroll
    for (int o = 8; o > 0; o >>= 1) rk[i] += __shfl_xor(rk[i], o);

  if (tl == 0) {
    const int rg = rt + tr;
    const size_t base = ((size_t)bh * nR + rg) * 8;
    bool dup = false;
#pragma unroll
    for (int i = 0; i < 6; ++i) {
      int p = rk[i];
      adjcol[base + i] = p;
      adjval[base + i] = sc[tr][p];
      dup = dup || (p == rg);
    }
    adjcol[base + 6] = rg;
    adjval[base + 6] = dup ? 0.f : sc[tr][rg];  // eye, min(.,1) dedup
    adjcol[base + 7] = rg;
    adjval[base + 7] = 0.f;                     // padding
  }
}

// ---------------- feats init: broadcast x over heads ---------------------------
__global__ void finit_k(const float* __restrict__ x, float* __restrict__ feats)
{
  size_t i = (size_t)blockIdx.x * 256 + threadIdx.x;  // float4 index
  constexpr size_t tot4 = (size_t)BH * nR * nT / 4;   // 5,120,000
  if (i < tot4) {
    size_t bh = i / (nR * nT / 4);
    size_t rem = i % (nR * nT / 4);
    size_t b = bh / nH;
    ((float4*)feats)[i] = ((const float4*)x)[b * (nR * nT / 4) + rem];
  }
}

// ---------------- sparse msg: msg[row,:] = sum_i val_i * feats[col_i,:] --------
__global__ __launch_bounds__(128) void spmsg_k(
    const int* __restrict__ adjcol, const float* __restrict__ adjval,
    const float* __restrict__ feats, float* __restrict__ msg)
{
  const int row = blockIdx.x;            // chunk-local: bh_local*400 + r
  const int bhl = row / nR;
  const size_t fbase = (size_t)bhl * nR * nT;
  const size_t b8 = (size_t)row * 8;
  int cols[7]; float vals[7];
#pragma unroll
  for (int i = 0; i < 7; ++i) { cols[i] = adjcol[b8 + i]; vals[i] = adjval[b8 + i]; }
  const int t = threadIdx.x;
  if (t < nT / 4) {
    const float4* f4 = (const float4*)(feats + fbase);
    float4 acc = {0.f, 0.f, 0.f, 0.f};
#pragma unroll
    for (int i = 0; i < 7; ++i) {
      float4 v = f4[(size_t)cols[i] * (nT / 4) + t];
      acc.x += vals[i] * v.x; acc.y += vals[i] * v.y;
      acc.z += vals[i] * v.z; acc.w += vals[i] * v.w;
    }
    ((float4*)(msg + (size_t)row * nT))[t] = acc;
  }
}

// ---------------- head fusion: fused = sum_h feats*fw[h] + fb ------------------
__global__ void hfuse_k(const float* __restrict__ feats, const float* __restrict__ fw,
                        const float* __restrict__ fb, float* __restrict__ fused)
{
  size_t i = (size_t)blockIdx.x * 256 + threadIdx.x;  // float4 over B*R*T
  constexpr size_t tot4 = (size_t)nB * nR * nT / 4;   // 640,000
  if (i >= tot4) return;
  size_t b = i / (nR * nT / 4);
  size_t rem = i % (nR * nT / 4);
  float fbv = fb[0];
  float4 acc = {fbv, fbv, fbv, fbv};
#pragma unroll
  for (int h = 0; h < nH; ++h) {
    float w = fw[h];
    float4 v = ((const float4*)feats)[(b * nH + h) * (nR * nT / 4) + rem];
    acc.x += w * v.x; acc.y += w * v.y; acc.z += w * v.z; acc.w += w * v.w;
  }
  ((float4*)fused)[i] = acc;
}

}  // namespace

extern "C" void kernel_launch(void* const* d_in, const int* in_sizes, int n_in,
                              void* d_out, int out_size, void* d_ws, size_t ws_size,
                              hipStream_t stream)
{
  (void)in_sizes; (void)n_in; (void)out_size; (void)ws_size;
  const float* x    = (const float*)d_in[0];
  const float* Wk   = (const float*)d_in[1];
  const float* bk   = (const float*)d_in[2];
  const float* seW1 = (const float*)d_in[3];
  const float* seb1 = (const float*)d_in[4];
  const float* seW2 = (const float*)d_in[5];
  const float* seb2 = (const float*)d_in[6];
  const float* gcnW = (const float*)d_in[7];
  const float* gcnb = (const float*)d_in[8];
  const float* fw   = (const float*)d_in[9];
  const float* fb   = (const float*)d_in[10];
  const float* mW1  = (const float*)d_in[11];
  const float* mb1  = (const float*)d_in[12];
  const float* mW2  = (const float*)d_in[13];
  const float* mb2  = (const float*)d_in[14];
  const float* mW3  = (const float*)d_in[15];
  const float* mb3  = (const float*)d_in[16];
  const float* mW4  = (const float*)d_in[17];
  const float* mb4  = (const float*)d_in[18];
  float* out = (float*)d_out;

  // workspace layout (floats); total ~139.3 MB
  float* ws     = (float*)d_ws;
  float* qk     = ws;                                  // 6400*512
  float* adjval = qk + (size_t)6400 * 512;             // 51200*8
  float* gate   = adjval + (size_t)51200 * 8;          // 64
  int*   adjcol = (int*)(gate + 64);                   // 51200*8
  float* feats  = gate + 64 + (size_t)51200 * 8;       // 128*400*400 = 20,480,000
  float* msg    = feats + (size_t)BH * nR * nT;        // 25600*400 = 10,240,000 (chunked)
  // MLP buffers alias the (dead-by-then) msg region:
  float* fused  = msg;                                 // 6400*400
  float* h1     = fused + (size_t)6400 * 400;          // 6400*256
  float* h2     = h1 + (size_t)6400 * 256;             // 6400*128
  float* h3     = h2 + (size_t)6400 * 128;             // 6400*64

  // 1. qk = x @ Wk + bk   [6400,400]@[400,512]
  gemm_k<128, 128, 16, 8, 8, false, false><<<dim3(4, 50), 256, 0, stream>>>(
      x, Wk, bk, nullptr, qk, 6400, 512, 400);

  // 2. SE gate (gap == 1/R identically)
  gate_k<<<1, 64, 0, stream>>>(seW1, seb1, seW2, seb2, gate);

  // 3. fused attention: scores -> relu -> softmax -> gate -> rank mask -> sparse adj
  attn_k<<<BH * 25, 256, 0, stream>>>(qk, gate, adjval, adjcol);

  // 4. feats = broadcast(x)
  finit_k<<<20000, 256, 0, stream>>>(x, feats);

  // 5. 8x GCN, chunked over (b,h) halves to bound msg scratch
  constexpr int chRows = 25600;  // 64 (b,h) * 400 rows
  for (int i = 0; i < 8; ++i) {
    for (int c = 0; c < 2; ++c) {
      const size_t ro = (size_t)c * chRows;
      spmsg_k<<<chRows, 128, 0, stream>>>(adjcol + ro * 8, adjval + ro * 8,
                                          feats + ro * nT, msg);
      gemm_k<128, 128, 16, 8, 8, true, true><<<dim3(4, chRows / 128), 256, 0, stream>>>(
          msg, gcnW + (size_t)i * nT * nT, gcnb + (size_t)i * nT,
          feats + ro * nT, feats + ro * nT, chRows, nT, nT);
    }
  }

  // 6. fuse heads
  hfuse_k<<<2500, 256, 0, stream>>>(feats, fw, fb, fused);

  // 7-10. MLP head (all relu)
  gemm_k<128, 128, 16, 8, 8, true, false><<<dim3(2, 50), 256, 0, stream>>>(
      fused, mW1, mb1, nullptr, h1, 6400, 256, 400);
  gemm_k<64, 64, 16, 4, 4, true, false><<<dim3(2, 100), 256, 0, stream>>>(
      h1, mW2, mb2, nullptr, h2, 6400, 128, 256);
  gemm_k<64, 64, 16, 4, 4, true, false><<<dim3(1, 100), 256, 0, stream>>>(
      h2, mW3, mb3, nullptr, h3, 6400, 64, 128);
  gemm_k<64, 64, 16, 4, 4, true, false><<<dim3(1, 100), 256, 0, stream>>>(
      h3, mW4, mb4, nullptr, out, 6400, 5, 64);
}

// Round 2
// 1719.073 us; speedup vs baseline: 2.2249x; 2.2249x over previous
//
#include <hip/hip_runtime.h>
#include <math.h>

namespace {

constexpr int nB = 16, nR = 400, nT = 400, nH = 8, nQ = 64;
constexpr int BH = nB * nH;   // 128
constexpr int HQ = nH * nQ;   // 512
constexpr int KP = 512;       // padded K/N for bf16 GEMM

typedef __attribute__((ext_vector_type(8))) short short8;
typedef __attribute__((ext_vector_type(4))) float floatx4;

__device__ __forceinline__ unsigned short f2bf(float f) {
  unsigned int u = __float_as_uint(f);
  unsigned int r = (u + 0x7fffu + ((u >> 16) & 1u)) >> 16;
  return (unsigned short)r;
}

__device__ __forceinline__ void gload16(const void* g, void* l) {
  __builtin_amdgcn_global_load_lds(
      (const __attribute__((address_space(1))) unsigned int*)g,
      (__attribute__((address_space(3))) unsigned int*)l, 16, 0, 0);
}

// ---------------- generic fp32 GEMM: C = act(A@W + bias) ----------------
template<int BM, int BN, int BK, int TM, int TN, bool RELU>
__global__ __launch_bounds__(256) void gemm_k(
    const float* __restrict__ A, const float* __restrict__ W,
    const float* __restrict__ bias,
    float* C, int M, int N, int K)
{
  constexpr int NT = (BM / TM) * (BN / TN);
  static_assert(NT == 256, "block must be 256 threads");
  __shared__ float As[BK][BM + 4];
  __shared__ float Bs[BK][BN + 4];
  const int tid = threadIdx.x;
  const int bm = blockIdx.y * BM;
  const int bn = blockIdx.x * BN;
  const int tx = tid % (BN / TN);
  const int ty = tid / (BN / TN);
  const bool n4ok = ((N & 3) == 0);

  float acc[TM][TN];
#pragma unroll
  for (int i = 0; i < TM; ++i)
#pragma unroll
    for (int j = 0; j < TN; ++j) acc[i][j] = 0.f;

  for (int kt = 0; kt < K; kt += BK) {
#pragma unroll
    for (int i = 0; i < (BM * BK) / (NT * 4); ++i) {
      int flat = (tid + i * NT) * 4;
      int m = flat / BK;
      int k = flat % BK;
      float4 v = *(const float4*)(A + (size_t)(bm + m) * K + kt + k);
      As[k + 0][m] = v.x; As[k + 1][m] = v.y;
      As[k + 2][m] = v.z; As[k + 3][m] = v.w;
    }
#pragma unroll
    for (int i = 0; i < (BK * BN) / (NT * 4); ++i) {
      int flat = (tid + i * NT) * 4;
      int k = flat / BN;
      int n = flat % BN;
      int gn = bn + n;
      float4 v;
      if (n4ok && gn + 3 < N) {
        v = *(const float4*)(W + (size_t)(kt + k) * N + gn);
      } else {
        v.x = (gn + 0 < N) ? W[(size_t)(kt + k) * N + gn + 0] : 0.f;
        v.y = (gn + 1 < N) ? W[(size_t)(kt + k) * N + gn + 1] : 0.f;
        v.z = (gn + 2 < N) ? W[(size_t)(kt + k) * N + gn + 2] : 0.f;
        v.w = (gn + 3 < N) ? W[(size_t)(kt + k) * N + gn + 3] : 0.f;
      }
      *(float4*)&Bs[k][n] = v;
    }
    __syncthreads();
#pragma unroll
    for (int k = 0; k < BK; ++k) {
      float a[TM], b[TN];
#pragma unroll
      for (int i = 0; i < TM; i += 4)
        *(float4*)&a[i] = *(const float4*)&As[k][ty * TM + i];
#pragma unroll
      for (int j = 0; j < TN; j += 4)
        *(float4*)&b[j] = *(const float4*)&Bs[k][tx * TN + j];
#pragma unroll
      for (int i = 0; i < TM; ++i)
#pragma unroll
        for (int j = 0; j < TN; ++j) acc[i][j] += a[i] * b[j];
    }
    __syncthreads();
  }

#pragma unroll
  for (int i = 0; i < TM; ++i) {
    const int gm = bm + ty * TM + i;
    float* crow = C + (size_t)gm * N;
#pragma unroll
    for (int j = 0; j < TN; j += 4) {
      const int gn = bn + tx * TN + j;
      if (n4ok && gn + 3 < N) {
        float4 bv = *(const float4*)(bias + gn);
        float4 v;
        v.x = acc[i][j + 0] + bv.x; v.y = acc[i][j + 1] + bv.y;
        v.z = acc[i][j + 2] + bv.z; v.w = acc[i][j + 3] + bv.w;
        if (RELU) {
          v.x = fmaxf(v.x, 0.f); v.y = fmaxf(v.y, 0.f);
          v.z = fmaxf(v.z, 0.f); v.w = fmaxf(v.w, 0.f);
        }
        *(float4*)(crow + gn) = v;
      } else {
#pragma unroll
        for (int jj = 0; jj < 4; ++jj) {
          int gnn = gn + jj;
          if (gnn < N) {
            float v = acc[i][j + jj] + bias[gnn];
            if (RELU) v = fmaxf(v, 0.f);
            crow[gnn] = v;
          }
        }
      }
    }
  }
}

// ---------------- bf16 MFMA GEMM for GCN layers -------------------------
__global__ __launch_bounds__(256) void gcn_gemm(
    const unsigned short* __restrict__ A,   // [M][512] bf16 (K-padded)
    const unsigned short* __restrict__ Bt,  // [512][512] bf16 n-major
    const float* __restrict__ bias,         // [400]
    float* __restrict__ C)                  // [M][400] fp32 in-place residual
{
  __shared__ __align__(128) unsigned short As[128 * 32];
  __shared__ __align__(128) unsigned short Bs[128 * 32];

  const int tid = threadIdx.x;
  const int lane = tid & 63;
  const int wave = tid >> 6;
  const int bm = blockIdx.y * 128;
  const int bn = blockIdx.x * 128;
  const int wm = (wave & 1) * 64;
  const int wn = (wave >> 1) * 64;

  floatx4 acc[4][4] = {};

  const int r0 = (wave * 2) * 16 + (lane >> 2);
  const int c0 = (lane & 3) * 8;
  const unsigned short* Ag0 = A + (size_t)(bm + r0) * KP + c0;
  const unsigned short* Ag1 = A + (size_t)(bm + r0 + 16) * KP + c0;
  const unsigned short* Bg0 = Bt + (size_t)(bn + r0) * KP + c0;
  const unsigned short* Bg1 = Bt + (size_t)(bn + r0 + 16) * KP + c0;
  unsigned short* Al0 = As + (wave * 2) * 512;
  unsigned short* Al1 = As + (wave * 2 + 1) * 512;
  unsigned short* Bl0 = Bs + (wave * 2) * 512;
  unsigned short* Bl1 = Bs + (wave * 2 + 1) * 512;

  const int fr = lane & 15;
  const int fk = (lane >> 4) * 8;

  for (int kt = 0; kt < KP; kt += 32) {
    gload16(Ag0 + kt, Al0);
    gload16(Ag1 + kt, Al1);
    gload16(Bg0 + kt, Bl0);
    gload16(Bg1 + kt, Bl1);
    __syncthreads();

    short8 a[4], b[4];
#pragma unroll
    for (int mi = 0; mi < 4; ++mi)
      a[mi] = *(const short8*)(As + (wm + mi * 16 + fr) * 32 + fk);
#pragma unroll
    for (int ni = 0; ni < 4; ++ni)
      b[ni] = *(const short8*)(Bs + (wn + ni * 16 + fr) * 32 + fk);
#pragma unroll
    for (int mi = 0; mi < 4; ++mi)
#pragma unroll
      for (int ni = 0; ni < 4; ++ni)
        acc[mi][ni] = __builtin_amdgcn_mfma_f32_16x16x32_bf16(
            a[mi], b[ni], acc[mi][ni], 0, 0, 0);
    __syncthreads();
  }

  float bv[4];
#pragma unroll
  for (int ni = 0; ni < 4; ++ni) {
    int gn = bn + wn + ni * 16 + (lane & 15);
    bv[ni] = (gn < nT) ? bias[gn] : 0.f;
  }
#pragma unroll
  for (int mi = 0; mi < 4; ++mi) {
    const int gmb = bm + wm + mi * 16 + (lane >> 4) * 4;
#pragma unroll
    for (int ni = 0; ni < 4; ++ni) {
      const int gn = bn + wn + ni * 16 + (lane & 15);
      if (gn < nT) {
#pragma unroll
        for (int r = 0; r < 4; ++r) {
          const size_t idx = (size_t)(gmb + r) * nT + gn;
          C[idx] = fmaxf(acc[mi][ni][r] + bv[ni], 0.f) + C[idx];
        }
      }
    }
  }
}

// ---------------- W prep: Wt[i][n][k] = bf16(gcn_W[i][k][n]), zero-padded ------
__global__ void wprep_k(const float* __restrict__ W, unsigned short* __restrict__ Wt)
{
  __shared__ float t[32][33];
  const int i = blockIdx.z;
  const int k0 = blockIdx.x * 32;
  const int n0 = blockIdx.y * 32;
  const int tx = threadIdx.x, ty = threadIdx.y;   // 32 x 8
#pragma unroll
  for (int r = 0; r < 32; r += 8) {
    int k = k0 + ty + r, n = n0 + tx;
    t[ty + r][tx] = (k < nT && n < nT) ? W[(size_t)i * nT * nT + (size_t)k * nT + n] : 0.f;
  }
  __syncthreads();
#pragma unroll
  for (int r = 0; r < 32; r += 8) {
    int n = n0 + ty + r, k = k0 + tx;
    Wt[(size_t)i * KP * KP + (size_t)n * KP + k] = f2bf(t[tx][ty + r]);
  }
}

// ---------------- SE gate (gap == 1/R identically) -----------------------------
__global__ void gate_k(const float* __restrict__ w1, const float* __restrict__ b1,
                       const float* __restrict__ w2, const float* __restrict__ b2,
                       float* gate)
{
  if (threadIdx.x == 0 && blockIdx.x == 0) {
    float h1[4];
    const float gap = 1.0f / 400.0f;
#pragma unroll
    for (int i = 0; i < 4; ++i) {
      float s = b1[i];
      for (int h = 0; h < 8; ++h) s += gap * w1[h * 4 + i];
      h1[i] = fmaxf(s, 0.f);
    }
#pragma unroll
    for (int h = 0; h < 8; ++h) {
      float s = b2[h];
      for (int i = 0; i < 4; ++i) s += h1[i] * w2[i * 8 + h];
      gate[h] = 1.f / (1.f + expf(-s));
    }
  }
}

// ---------------- fused scores -> relu -> softmax -> gate -> stable-rank mask --
__global__ __launch_bounds__(256) void attn_k(
    const float* __restrict__ qk, const float* __restrict__ gate,
    float* __restrict__ adjval, int* __restrict__ adjcol)
{
  __shared__ float Qs[16][68];
  __shared__ float Ks[64][68];
  __shared__ float sc[16][404];

  const int tid = threadIdx.x;
  const int blk = blockIdx.x;
  const int bh = blk / 25;
  const int rt = (blk % 25) * 16;
  const int b = bh / nH;
  const int h = bh % nH;
  const float* qkb = qk + (size_t)b * nR * HQ + h * nQ;

  {
    int r = tid >> 4;
    int q = (tid & 15) << 2;
    *(float4*)&Qs[r][q] = *(const float4*)(qkb + (size_t)(rt + r) * HQ + q);
  }

  const int r0 = (tid & 7) * 2;
  const int s0 = (tid >> 3) * 2;

  for (int st = 0; st < 7; ++st) {
    const int sn = st * 64;
    const int cnt = (nR - sn < 64) ? (nR - sn) : 64;
    __syncthreads();
#pragma unroll
    for (int i = 0; i < 4; ++i) {
      int flat = (tid + i * 256) * 4;
      int j = flat >> 6;
      int q = flat & 63;
      if (j < cnt)
        *(float4*)&Ks[j][q] = *(const float4*)(qkb + (size_t)(sn + j) * HQ + q);
    }
    __syncthreads();
    float a00 = 0.f, a01 = 0.f, a10 = 0.f, a11 = 0.f;
#pragma unroll
    for (int q4 = 0; q4 < 16; ++q4) {
      float4 qa = *(const float4*)&Qs[r0][q4 * 4];
      float4 qb = *(const float4*)&Qs[r0 + 1][q4 * 4];
      float4 ka = *(const float4*)&Ks[s0][q4 * 4];
      float4 kb = *(const float4*)&Ks[s0 + 1][q4 * 4];
      a00 += qa.x * ka.x + qa.y * ka.y + qa.z * ka.z + qa.w * ka.w;
      a01 += qa.x * kb.x + qa.y * kb.y + qa.z * kb.z + qa.w * kb.w;
      a10 += qb.x * ka.x + qb.y * ka.y + qb.z * ka.z + qb.w * ka.w;
      a11 += qb.x * kb.x + qb.y * kb.y + qb.z * kb.z + qb.w * kb.w;
    }
    if (s0 < cnt) {
      sc[r0][sn + s0]     = fmaxf(a00 * 0.125f, 0.f);
      sc[r0 + 1][sn + s0] = fmaxf(a10 * 0.125f, 0.f);
    }
    if (s0 + 1 < cnt) {
      sc[r0][sn + s0 + 1]     = fmaxf(a01 * 0.125f, 0.f);
      sc[r0 + 1][sn + s0 + 1] = fmaxf(a11 * 0.125f, 0.f);
    }
  }
  __syncthreads();

  const int tr = tid >> 4;
  const int tl = tid & 15;
  float m = 0.f;
  for (int j = tl; j < nR; j += 16) m = fmaxf(m, sc[tr][j]);
#pragma unroll
  for (int o = 8; o > 0; o >>= 1) m = fmaxf(m, __shfl_xor(m, o));
  float ssum = 0.f;
  for (int j = tl; j < nR; j += 16) {
    float e = expf(sc[tr][j] - m);
    sc[tr][j] = e;
    ssum += e;
  }
#pragma unroll
  for (int o = 8; o > 0; o >>= 1) ssum += __shfl_xor(ssum, o);
  const float g = gate[h];
  for (int j = tl; j < nR; j += 16) sc[tr][j] = (sc[tr][j] / ssum) * g;
  __syncthreads();

  const int csp[6] = {0, 16, 17, 18, 19, 20};
  float vc[6];
#pragma unroll
  for (int i = 0; i < 6; ++i) vc[i] = sc[tr][csp[i]];
  int rk[6] = {0, 0, 0, 0, 0, 0};
  for (int j = tl; j < nR; j += 16) {
    float vj = sc[tr][j];
#pragma unroll
    for (int i = 0; i < 6; ++i)
      rk[i] += (vj < vc[i]) ? 1 : ((vj == vc[i] && j < csp[i]) ? 1 : 0);
  }
#pragma unroll
  for (int i = 0; i < 6; ++i)
#pragma unroll
    for (int o = 8; o > 0; o >>= 1) rk[i] += __shfl_xor(rk[i], o);

  if (tl == 0) {
    const int rg = rt + tr;
    const size_t base = ((size_t)bh * nR + rg) * 8;
    bool dup = false;
#pragma unroll
    for (int i = 0; i < 6; ++i) {
      int p = rk[i];
      adjcol[base + i] = p;
      adjval[base + i] = sc[tr][p];
      dup = dup || (p == rg);
    }
    adjcol[base + 6] = rg;
    adjval[base + 6] = dup ? 0.f : sc[tr][rg];
    adjcol[base + 7] = rg;
    adjval[base + 7] = 0.f;
  }
}

// ---------------- feats init ----------------------------------------------------
__global__ void finit_k(const float* __restrict__ x, float* __restrict__ feats)
{
  size_t i = (size_t)blockIdx.x * 256 + threadIdx.x;
  constexpr size_t tot4 = (size_t)BH * nR * nT / 4;
  if (i < tot4) {
    size_t bh = i / (nR * nT / 4);
    size_t rem = i % (nR * nT / 4);
    size_t b = bh / nH;
    ((float4*)feats)[i] = ((const float4*)x)[b * (nR * nT / 4) + rem];
  }
}

// ---------------- sparse msg (bf16 out, K-padded): 2 rows per block -------------
__global__ __launch_bounds__(256) void spmsg_k(
    const int* __restrict__ adjcol, const float* __restrict__ adjval,
    const float* __restrict__ feats, unsigned short* __restrict__ msg)
{
  const int row = blockIdx.x * 2 + (threadIdx.x >> 7);
  const int c4 = threadIdx.x & 127;
  unsigned short* orow = msg + (size_t)row * KP + c4 * 4;
  if (c4 >= 100) {
    *(ushort4*)orow = make_ushort4(0, 0, 0, 0);
    return;
  }
  const int bhl = row / nR;
  const size_t b8 = (size_t)row * 8;
  const float4* f4 = (const float4*)(feats + (size_t)bhl * nR * nT);
  float4 acc = {0.f, 0.f, 0.f, 0.f};
#pragma unroll
  for (int i = 0; i < 7; ++i) {
    int col = adjcol[b8 + i];
    float val = adjval[b8 + i];
    float4 v = f4[(size_t)col * 100 + c4];
    acc.x += val * v.x; acc.y += val * v.y;
    acc.z += val * v.z; acc.w += val * v.w;
  }
  *(ushort4*)orow = make_ushort4(f2bf(acc.x), f2bf(acc.y), f2bf(acc.z), f2bf(acc.w));
}

// ---------------- head fusion ---------------------------------------------------
__global__ void hfuse_k(const float* __restrict__ feats, const float* __restrict__ fw,
                        const float* __restrict__ fb, float* __restrict__ fused)
{
  size_t i = (size_t)blockIdx.x * 256 + threadIdx.x;
  constexpr size_t tot4 = (size_t)nB * nR * nT / 4;
  if (i >= tot4) return;
  size_t b = i / (nR * nT / 4);
  size_t rem = i % (nR * nT / 4);
  float fbv = fb[0];
  float4 acc = {fbv, fbv, fbv, fbv};
#pragma unroll
  for (int h = 0; h < nH; ++h) {
    float w = fw[h];
    float4 v = ((const float4*)feats)[(b * nH + h) * (nR * nT / 4) + rem];
    acc.x += w * v.x; acc.y += w * v.y; acc.z += w * v.z; acc.w += w * v.w;
  }
  ((float4*)fused)[i] = acc;
}

}  // namespace

extern "C" void kernel_launch(void* const* d_in, const int* in_sizes, int n_in,
                              void* d_out, int out_size, void* d_ws, size_t ws_size,
                              hipStream_t stream)
{
  (void)in_sizes; (void)n_in; (void)out_size; (void)ws_size;
  const float* x    = (const float*)d_in[0];
  const float* Wk   = (const float*)d_in[1];
  const float* bk   = (const float*)d_in[2];
  const float* seW1 = (const float*)d_in[3];
  const float* seb1 = (const float*)d_in[4];
  const float* seW2 = (const float*)d_in[5];
  const float* seb2 = (const float*)d_in[6];
  const float* gcnW = (const float*)d_in[7];
  const float* gcnb = (const float*)d_in[8];
  const float* fw   = (const float*)d_in[9];
  const float* fb   = (const float*)d_in[10];
  const float* mW1  = (const float*)d_in[11];
  const float* mb1  = (const float*)d_in[12];
  const float* mW2  = (const float*)d_in[13];
  const float* mb2  = (const float*)d_in[14];
  const float* mW3  = (const float*)d_in[15];
  const float* mb3  = (const float*)d_in[16];
  const float* mW4  = (const float*)d_in[17];
  const float* mb4  = (const float*)d_in[18];
  float* out = (float*)d_out;

  // workspace layout (float units); ~129 MB total
  float* ws     = (float*)d_ws;
  float* qk     = ws;                                    // 3,276,800 f
  float* adjval = qk + (size_t)6400 * 512;               //   409,600 f
  float* gate   = adjval + (size_t)51200 * 8;            //        64 f
  int*   adjcol = (int*)(gate + 64);                     //   409,600 i
  float* p      = gate + 64 + (size_t)51200 * 8;
  unsigned short* Wt = (unsigned short*)p;               // 8*512*512 shorts = 1,048,576 f
  float* feats  = p + (size_t)8 * KP * KP / 2;           // 20,480,000 f
  unsigned short* msg = (unsigned short*)(feats + (size_t)BH * nR * nT); // 25600*512 sh
  float* fused  = (float*)msg;                           // aliases dead msg region
  float* h1     = fused + (size_t)6400 * 400;
  float* h2     = h1 + (size_t)6400 * 256;
  float* h3     = h2 + (size_t)6400 * 128;

  // 0. gcn_W -> bf16, transposed (n-major) + zero-padded to 512x512
  wprep_k<<<dim3(16, 16, 8), dim3(32, 8), 0, stream>>>(gcnW, Wt);

  // 1. qk = x @ Wk + bk
  gemm_k<128, 128, 16, 8, 8, false><<<dim3(4, 50), 256, 0, stream>>>(
      x, Wk, bk, qk, 6400, 512, 400);

  // 2. SE gate
  gate_k<<<1, 64, 0, stream>>>(seW1, seb1, seW2, seb2, gate);

  // 3. attention -> 7-sparse adjacency (fp32, rank-exact)
  attn_k<<<BH * 25, 256, 0, stream>>>(qk, gate, adjval, adjcol);

  // 4. feats = broadcast(x)
  finit_k<<<20000, 256, 0, stream>>>(x, feats);

  // 5. 8x GCN with bf16 MFMA GEMM, chunked over (b,h) halves
  constexpr int chRows = 25600;
  for (int i = 0; i < 8; ++i) {
    for (int c = 0; c < 2; ++c) {
      const size_t ro = (size_t)c * chRows;
      spmsg_k<<<chRows / 2, 256, 0, stream>>>(adjcol + ro * 8, adjval + ro * 8,
                                              feats + ro * nT, msg);
      gcn_gemm<<<dim3(4, chRows / 128), 256, 0, stream>>>(
          msg, Wt + (size_t)i * KP * KP, gcnb + (size_t)i * nT, feats + ro * nT);
    }
  }

  // 6. fuse heads
  hfuse_k<<<2500, 256, 0, stream>>>(feats, fw, fb, fused);

  // 7-10. MLP head (fp32)
  gemm_k<128, 128, 16, 8, 8, true><<<dim3(2, 50), 256, 0, stream>>>(
      fused, mW1, mb1, h1, 6400, 256, 400);
  gemm_k<64, 64, 16, 4, 4, true><<<dim3(2, 100), 256, 0, stream>>>(
      h1, mW2, mb2, h2, 6400, 128, 256);
  gemm_k<64, 64, 16, 4, 4, true><<<dim3(1, 100), 256, 0, stream>>>(
      h2, mW3, mb3, h3, 6400, 64, 128);
  gemm_k<64, 64, 16, 4, 4, true><<<dim3(1, 100), 256, 0, stream>>>(
      h3, mW4, mb4, out, 6400, 5, 64);
}